// Round 4
// baseline (1012.920 us; speedup 1.0000x reference)
//
#include <hip/hip_runtime.h>
#include <stdint.h>

#define F_NODE 128
#define F_EDGE 32
#define HID    128
#define OUTF   64

// ---------------------------------------------------------------------------
// Preprocessing kernels
// ---------------------------------------------------------------------------

// Detect whether edge_index is int64 (reference dtype) or int32.
__global__ void detect_kernel(const void* ei, int N, int* flag) {
    const long long* p64 = (const long long*)ei;
    int t = threadIdx.x;
    long long v = p64[t];
    int ok = (v >= 0 && v < (long long)N) ? 1 : 0;
    unsigned long long m = __ballot(ok);
    if (t == 0) *flag = (__popcll(m) >= 32) ? 1 : 0;
}

__global__ void decode_kernel(const void* ei, int E, int N, const int* flag,
                              int* __restrict__ row, int* __restrict__ col) {
    int i = blockIdx.x * blockDim.x + threadIdx.x;
    if (i >= E) return;
    int r, c;
    if (*flag) {
        const long long* p = (const long long*)ei;
        r = (int)p[i];
        c = (int)p[E + i];
    } else {
        const int* p = (const int*)ei;
        r = p[i];
        c = p[E + i];
    }
    r = min(max(r, 0), N - 1);
    c = min(max(c, 0), N - 1);
    row[i] = r;
    col[i] = c;
}

__global__ void zero_kernel(int* p, int n) {
    int i = blockIdx.x * blockDim.x + threadIdx.x;
    if (i < n) p[i] = 0;
}

// cnt[0..N)   = in-degree  (col histogram)  -> dst-CSR
// cnt[N..2N)  = out-degree (row histogram)  -> row-CSR (for agg gather)
__global__ void hist_kernel(const int* __restrict__ row, const int* __restrict__ col,
                            int E, int N, int* __restrict__ cnt) {
    int i = blockIdx.x * blockDim.x + threadIdx.x;
    if (i < E) {
        atomicAdd(&cnt[col[i]], 1);
        atomicAdd(&cnt[N + row[i]], 1);
    }
}

// 3-step exclusive scan over cnt[M] -> offs[M+1]
__global__ void scan1_kernel(const int* __restrict__ cnt, int M,
                             int* __restrict__ offs, int* __restrict__ bsum) {
    __shared__ int s[1024];
    int t = threadIdx.x;
    int i = blockIdx.x * 1024 + t;
    int v = (i < M) ? cnt[i] : 0;
    s[t] = v;
    __syncthreads();
    for (int d = 1; d < 1024; d <<= 1) {
        int x = (t >= d) ? s[t - d] : 0;
        __syncthreads();
        s[t] += x;
        __syncthreads();
    }
    if (i < M) offs[i + 1] = s[t];
    if (t == 1023) bsum[blockIdx.x] = s[1023];
}

__global__ void scan2_kernel(int* bsum, int nb) {
    __shared__ int s[1024];
    int t = threadIdx.x;
    int v = (t < nb) ? bsum[t] : 0;
    s[t] = v;
    __syncthreads();
    for (int d = 1; d < 1024; d <<= 1) {
        int x = (t >= d) ? s[t - d] : 0;
        __syncthreads();
        s[t] += x;
        __syncthreads();
    }
    if (t < nb) bsum[t] = s[t] - v;
}

__global__ void scan3_kernel(int* offs, int M, const int* __restrict__ bsum) {
    int i = blockIdx.x * blockDim.x + threadIdx.x;
    if (i == 0) offs[0] = 0;
    if (i < M) offs[i + 1] += bsum[i >> 10];
}

__global__ void init_kernel(const int* __restrict__ cnt, const int* __restrict__ offs,
                            int N, int* __restrict__ cursor, float* __restrict__ dinv) {
    int i = blockIdx.x * blockDim.x + threadIdx.x;
    if (i < 2 * N) {
        cursor[i] = offs[i];
        if (i < N) dinv[i] = rsqrtf((float)(cnt[i] + 1));  // +1 self loop
    }
}

// Fill both CSRs: dst-CSR gets (src, norm); row-CSR gets edge id.
__global__ void fill_kernel(const int* __restrict__ row, const int* __restrict__ col,
                            int E, int N, int* __restrict__ cursor,
                            const float* __restrict__ dinv,
                            int2* __restrict__ ent, int* __restrict__ eid) {
    int i = blockIdx.x * blockDim.x + threadIdx.x;
    if (i >= E) return;
    int r = row[i], c = col[i];
    int pc = atomicAdd(&cursor[c], 1);
    ent[pc] = make_int2(r, __float_as_int(dinv[r] * dinv[c]));
    int pr = atomicAdd(&cursor[N + r], 1);   // absolute pos in [E, 2E)
    eid[pr - E] = i;
}

// agg[n] = sum of edge_attr rows over out-edges of n (row-CSR gather, no atomics)
__global__ __launch_bounds__(256) void aggr_kernel(const float* __restrict__ ea,
                                                   const int* __restrict__ offs,
                                                   const int* __restrict__ eid,
                                                   int N, int E,
                                                   float* __restrict__ agg) {
    int wid  = threadIdx.x >> 6;
    int lane = threadIdx.x & 63;
    int n = blockIdx.x * 4 + wid;
    if (n >= N) return;
    int f  = lane & 31;
    int hh = lane >> 5;
    int r0 = offs[N + n] - E;
    int r1 = offs[N + n + 1] - E;
    float s = 0.f;
    int e = r0 + hh;
    for (; e + 2 < r1; e += 4) {     // each half-wave: e, e+2 in flight
        float x0 = ea[(size_t)eid[e] * F_EDGE + f];
        float x1 = ea[(size_t)eid[e + 2] * F_EDGE + f];
        s += x0 + x1;
    }
    if (e < r1) s += ea[(size_t)eid[e] * F_EDGE + f];
    s += __shfl(s, lane ^ 32);
    if (hh == 0) agg[(size_t)n * F_EDGE + f] = s;
}

// ---------------------------------------------------------------------------
// GEMM: out[N,F] = concat(A[N,128], B[N,32]) @ W[160,F]
// ---------------------------------------------------------------------------
template <int F, int BN, int TX>
__global__ __launch_bounds__(256) void gemm_kernel(const float* __restrict__ A,
                                                   const float* __restrict__ B,
                                                   const float* __restrict__ W,
                                                   float* __restrict__ outp, int N) {
    constexpr int TY  = 256 / TX;
    constexpr int NPT = BN / TY;
    constexpr int KC  = 32;
    constexpr int IST = KC + 4;
    constexpr int WST = F + 4;
    __shared__ float in_lds[BN][IST];
    __shared__ float w_lds[KC][WST];

    int t  = threadIdx.x;
    int tx = t % TX;
    int ty = t / TX;
    int n0 = blockIdx.x * BN;
    int j0 = tx * 8;

    float acc[NPT][8];
#pragma unroll
    for (int i = 0; i < NPT; ++i)
#pragma unroll
        for (int f = 0; f < 8; ++f) acc[i][f] = 0.f;

    for (int c = 0; c < 5; ++c) {
        const float* src = (c < 4) ? (A + c * KC) : B;
        int stride = (c < 4) ? F_NODE : F_EDGE;
        for (int l = t; l < BN * 8; l += 256) {
            int rr = l >> 3;
            int cc = (l & 7) * 4;
            int n = n0 + rr;
            if (n >= N) n = N - 1;
            float4 v = *(const float4*)(src + (size_t)n * stride + cc);
            *(float4*)&in_lds[rr][cc] = v;
        }
        for (int l = t; l < KC * F / 4; l += 256) {
            int rr = l / (F / 4);
            int cc = (l % (F / 4)) * 4;
            float4 v = *(const float4*)(W + (size_t)(c * KC + rr) * F + cc);
            *(float4*)&w_lds[rr][cc] = v;
        }
        __syncthreads();

#pragma unroll
        for (int kk = 0; kk < KC; kk += 4) {
            float4 a4[NPT];
#pragma unroll
            for (int i = 0; i < NPT; ++i)
                a4[i] = *(const float4*)&in_lds[ty * NPT + i][kk];
#pragma unroll
            for (int p = 0; p < 4; ++p) {
                float4 wa = *(const float4*)&w_lds[kk + p][j0];
                float4 wb = *(const float4*)&w_lds[kk + p][j0 + 4];
#pragma unroll
                for (int i = 0; i < NPT; ++i) {
                    float a = (p == 0) ? a4[i].x : (p == 1) ? a4[i].y
                              : (p == 2) ? a4[i].z : a4[i].w;
                    acc[i][0] = fmaf(a, wa.x, acc[i][0]);
                    acc[i][1] = fmaf(a, wa.y, acc[i][1]);
                    acc[i][2] = fmaf(a, wa.z, acc[i][2]);
                    acc[i][3] = fmaf(a, wa.w, acc[i][3]);
                    acc[i][4] = fmaf(a, wb.x, acc[i][4]);
                    acc[i][5] = fmaf(a, wb.y, acc[i][5]);
                    acc[i][6] = fmaf(a, wb.z, acc[i][6]);
                    acc[i][7] = fmaf(a, wb.w, acc[i][7]);
                }
            }
        }
        __syncthreads();
    }

#pragma unroll
    for (int i = 0; i < NPT; ++i) {
        int n = n0 + ty * NPT + i;
        if (n < N) {
            *(float4*)(outp + (size_t)n * F + j0) =
                make_float4(acc[i][0], acc[i][1], acc[i][2], acc[i][3]);
            *(float4*)(outp + (size_t)n * F + j0 + 4) =
                make_float4(acc[i][4], acc[i][5], acc[i][6], acc[i][7]);
        }
    }
}

// ---------------------------------------------------------------------------
// Conv aggregation: out[n] = sum_{e: dst==n} norm_e * h[src_e] + dinv[n]^2*h[n] + b
// One wave per node; CSR gather, 4 gathers in flight (ILP unroll).
// ---------------------------------------------------------------------------
template <int F, bool RELU>
__global__ __launch_bounds__(256) void conv_kernel(const float* __restrict__ h,
                                                   const int* __restrict__ offs,
                                                   const int2* __restrict__ ent,
                                                   const float* __restrict__ dinv,
                                                   const float* __restrict__ bias,
                                                   float* __restrict__ outp, int N) {
    int wid  = threadIdx.x >> 6;
    int lane = threadIdx.x & 63;
    int n = blockIdx.x * 4 + wid;
    if (n >= N) return;
    float dn = dinv[n];
    float sw = dn * dn;
    int e0 = offs[n], e1 = offs[n + 1];

    if constexpr (F == 128) {
        float2 hv = *((const float2*)(h + (size_t)n * F) + lane);
        float a0 = sw * hv.x, a1 = sw * hv.y;
        int e = e0;
        for (; e + 4 <= e1; e += 4) {
            int2 p0 = ent[e], p1 = ent[e + 1], p2 = ent[e + 2], p3 = ent[e + 3];
            float2 v0 = *((const float2*)(h + (size_t)p0.x * F) + lane);
            float2 v1 = *((const float2*)(h + (size_t)p1.x * F) + lane);
            float2 v2 = *((const float2*)(h + (size_t)p2.x * F) + lane);
            float2 v3 = *((const float2*)(h + (size_t)p3.x * F) + lane);
            float w0 = __int_as_float(p0.y), w1 = __int_as_float(p1.y);
            float w2 = __int_as_float(p2.y), w3 = __int_as_float(p3.y);
            a0 = fmaf(w0, v0.x, a0); a1 = fmaf(w0, v0.y, a1);
            a0 = fmaf(w1, v1.x, a0); a1 = fmaf(w1, v1.y, a1);
            a0 = fmaf(w2, v2.x, a0); a1 = fmaf(w2, v2.y, a1);
            a0 = fmaf(w3, v3.x, a0); a1 = fmaf(w3, v3.y, a1);
        }
        for (; e < e1; ++e) {
            int2 pr = ent[e];
            float w = __int_as_float(pr.y);
            float2 v = *((const float2*)(h + (size_t)pr.x * F) + lane);
            a0 = fmaf(w, v.x, a0);
            a1 = fmaf(w, v.y, a1);
        }
        float2 bv = *((const float2*)bias + lane);
        a0 += bv.x;
        a1 += bv.y;
        if (RELU) { a0 = fmaxf(a0, 0.f); a1 = fmaxf(a1, 0.f); }
        *((float2*)(outp + (size_t)n * F) + lane) = make_float2(a0, a1);
    } else {
        float a0 = sw * h[(size_t)n * F + lane];
        int e = e0;
        for (; e + 4 <= e1; e += 4) {
            int2 p0 = ent[e], p1 = ent[e + 1], p2 = ent[e + 2], p3 = ent[e + 3];
            float v0 = h[(size_t)p0.x * F + lane];
            float v1 = h[(size_t)p1.x * F + lane];
            float v2 = h[(size_t)p2.x * F + lane];
            float v3 = h[(size_t)p3.x * F + lane];
            a0 = fmaf(__int_as_float(p0.y), v0, a0);
            a0 = fmaf(__int_as_float(p1.y), v1, a0);
            a0 = fmaf(__int_as_float(p2.y), v2, a0);
            a0 = fmaf(__int_as_float(p3.y), v3, a0);
        }
        for (; e < e1; ++e) {
            int2 pr = ent[e];
            a0 = fmaf(__int_as_float(pr.y), h[(size_t)pr.x * F + lane], a0);
        }
        a0 += bias[lane];
        if (RELU) a0 = fmaxf(a0, 0.f);
        outp[(size_t)n * F + lane] = a0;
    }
}

// ---------------------------------------------------------------------------
extern "C" void kernel_launch(void* const* d_in, const int* in_sizes, int n_in,
                              void* d_out, int out_size, void* d_ws, size_t ws_size,
                              hipStream_t stream) {
    const float* x  = (const float*)d_in[0];
    const void*  ei = d_in[1];
    const float* ea = (const float*)d_in[2];
    const float* w1 = (const float*)d_in[3];
    const float* b1 = (const float*)d_in[4];
    const float* w2 = (const float*)d_in[5];
    const float* b2 = (const float*)d_in[6];
    float* out = (float*)d_out;

    int N = in_sizes[0] / F_NODE;
    int E = in_sizes[1] / 2;

    char* ws = (char*)d_ws;
    size_t off = 0;
    auto alloc = [&](size_t bytes) -> void* {
        void* p = ws + off;
        off = (off + bytes + 255) & ~(size_t)255;
        return p;
    };

    int*   flag   = (int*)alloc(256);
    int*   row    = (int*)alloc((size_t)E * 4);
    int*   col    = (int*)alloc((size_t)E * 4);
    int*   cnt    = (int*)alloc((size_t)2 * N * 4);
    int*   offs   = (int*)alloc((size_t)(2 * N + 1) * 4);
    int*   cursor = (int*)alloc((size_t)2 * N * 4);
    float* dinv   = (float*)alloc((size_t)N * 4);
    int*   bsum   = (int*)alloc(4096);
    int2*  ent    = (int2*)alloc((size_t)E * 8);
    int*   eid    = (int*)alloc((size_t)E * 4);
    float* agg    = (float*)alloc((size_t)N * F_EDGE * 4);
    float* h1     = (float*)alloc((size_t)N * HID * 4);
    float* hr     = (float*)alloc((size_t)N * HID * 4);
    float* h2     = (float*)alloc((size_t)N * OUTF * 4);

    int gE = (E + 255) / 256;
    int M  = 2 * N;                       // concatenated histogram length
    int gM = (M + 255) / 256;
    int nb = (M + 1023) / 1024;

    detect_kernel<<<1, 64, 0, stream>>>(ei, N, flag);
    decode_kernel<<<gE, 256, 0, stream>>>(ei, E, N, flag, row, col);
    zero_kernel<<<gM, 256, 0, stream>>>(cnt, M);
    hist_kernel<<<gE, 256, 0, stream>>>(row, col, E, N, cnt);
    scan1_kernel<<<nb, 1024, 0, stream>>>(cnt, M, offs, bsum);
    scan2_kernel<<<1, 1024, 0, stream>>>(bsum, nb);
    scan3_kernel<<<gM, 256, 0, stream>>>(offs, M, bsum);
    init_kernel<<<gM, 256, 0, stream>>>(cnt, offs, N, cursor, dinv);
    fill_kernel<<<gE, 256, 0, stream>>>(row, col, E, N, cursor, dinv, ent, eid);
    aggr_kernel<<<(N + 3) / 4, 256, 0, stream>>>(ea, offs, eid, N, E, agg);

    gemm_kernel<HID, 64, 16><<<(N + 63) / 64, 256, 0, stream>>>(x, agg, w1, h1, N);
    conv_kernel<HID, true><<<(N + 3) / 4, 256, 0, stream>>>(h1, offs, ent, dinv, b1, hr, N);
    gemm_kernel<OUTF, 128, 8><<<(N + 127) / 128, 256, 0, stream>>>(hr, agg, w2, h2, N);
    conv_kernel<OUTF, false><<<(N + 3) / 4, 256, 0, stream>>>(h2, offs, ent, dinv, b2, out, N);
}

// Round 5
// 911.053 us; speedup vs baseline: 1.1118x; 1.1118x over previous
//
#include <hip/hip_runtime.h>
#include <stdint.h>

#define F_NODE 128
#define F_EDGE 32
#define HID    128
#define OUTF   64

#define NBMAX  1024     // max coarse buckets (supports N <= 131072)
#define CE     16384    // edges per binscat block

// ---------------------------------------------------------------------------
// Preprocessing kernels
// ---------------------------------------------------------------------------

// Detect whether edge_index is int64 (reference dtype) or int32.
__global__ void detect_kernel(const void* ei, int N, int* flag) {
    const long long* p64 = (const long long*)ei;
    int t = threadIdx.x;
    long long v = p64[t];
    int ok = (v >= 0 && v < (long long)N) ? 1 : 0;
    unsigned long long m = __ballot(ok);
    if (t == 0) *flag = (__popcll(m) >= 32) ? 1 : 0;
}

__global__ void decode_kernel(const void* ei, int E, int N, const int* flag,
                              int* __restrict__ row, int* __restrict__ col) {
    int i = blockIdx.x * blockDim.x + threadIdx.x;
    if (i >= E) return;
    int r, c;
    if (*flag) {
        const long long* p = (const long long*)ei;
        r = (int)p[i];
        c = (int)p[E + i];
    } else {
        const int* p = (const int*)ei;
        r = p[i];
        c = p[E + i];
    }
    r = min(max(r, 0), N - 1);
    c = min(max(c, 0), N - 1);
    row[i] = r;
    col[i] = c;
}

__global__ void zero_kernel(int* p, int n) {
    int i = blockIdx.x * blockDim.x + threadIdx.x;
    if (i < n) p[i] = 0;
}

// cnt[0..N)   = in-degree  (col histogram)  -> dst-CSR
// cnt[N..2N)  = out-degree (row histogram)  -> row-CSR (for agg gather)
__global__ void hist_kernel(const int* __restrict__ row, const int* __restrict__ col,
                            int E, int N, int* __restrict__ cnt) {
    int i = blockIdx.x * blockDim.x + threadIdx.x;
    if (i < E) {
        atomicAdd(&cnt[col[i]], 1);
        atomicAdd(&cnt[N + row[i]], 1);
    }
}

// 3-step exclusive scan over cnt[M] -> offs[M+1]
__global__ void scan1_kernel(const int* __restrict__ cnt, int M,
                             int* __restrict__ offs, int* __restrict__ bsum) {
    __shared__ int s[1024];
    int t = threadIdx.x;
    int i = blockIdx.x * 1024 + t;
    int v = (i < M) ? cnt[i] : 0;
    s[t] = v;
    __syncthreads();
    for (int d = 1; d < 1024; d <<= 1) {
        int x = (t >= d) ? s[t - d] : 0;
        __syncthreads();
        s[t] += x;
        __syncthreads();
    }
    if (i < M) offs[i + 1] = s[t];
    if (t == 1023) bsum[blockIdx.x] = s[1023];
}

__global__ void scan2_kernel(int* bsum, int nb) {
    __shared__ int s[1024];
    int t = threadIdx.x;
    int v = (t < nb) ? bsum[t] : 0;
    s[t] = v;
    __syncthreads();
    for (int d = 1; d < 1024; d <<= 1) {
        int x = (t >= d) ? s[t - d] : 0;
        __syncthreads();
        s[t] += x;
        __syncthreads();
    }
    if (t < nb) bsum[t] = s[t] - v;
}

__global__ void scan3_kernel(int* offs, int M, const int* __restrict__ bsum) {
    int i = blockIdx.x * blockDim.x + threadIdx.x;
    if (i == 0) offs[0] = 0;
    if (i < M) offs[i + 1] += bsum[i >> 10];
}

__global__ void dinv_kernel(const int* __restrict__ cnt, int N, float* __restrict__ dinv) {
    int i = blockIdx.x * blockDim.x + threadIdx.x;
    if (i < N) dinv[i] = rsqrtf((float)(cnt[i] + 1));   // +1 self loop
}

// Coarse bucket counts: ccnt[s*NB + b] = sum of cnt[s*N + b*128 .. +128)
__global__ void coarse_cnt_kernel(const int* __restrict__ cnt, int N, int NB,
                                  int* __restrict__ ccnt) {
    __shared__ int s[128];
    int bi  = blockIdx.x;
    int srt = bi / NB;
    int b   = bi % NB;
    int idx = b * 128 + threadIdx.x;
    s[threadIdx.x] = (idx < N) ? cnt[srt * N + idx] : 0;
    __syncthreads();
    for (int d = 64; d > 0; d >>= 1) {
        if (threadIdx.x < d) s[threadIdx.x] += s[threadIdx.x + d];
        __syncthreads();
    }
    if (threadIdx.x == 0) ccnt[bi] = s[0];
}

// Exclusive scan of each NB-segment of ccnt -> cbase (and cursor copy ccur)
__global__ void coarse_scan_kernel(const int* __restrict__ ccnt, int NB,
                                   int* __restrict__ cbase, int* __restrict__ ccur) {
    __shared__ int s[1024];
    int t = threadIdx.x;
    for (int seg = 0; seg < 2; ++seg) {
        int v = (t < NB) ? ccnt[seg * NB + t] : 0;
        s[t] = v;
        __syncthreads();
        for (int d = 1; d < 1024; d <<= 1) {
            int x = (t >= d) ? s[t - d] : 0;
            __syncthreads();
            s[t] += x;
            __syncthreads();
        }
        if (t < NB) {
            int ex = s[t] - v;
            cbase[seg * NB + t] = ex;
            ccur[seg * NB + t]  = ex;
        }
        __syncthreads();
    }
}

// Phase C: binned scatter. Each block takes CE edges, builds LDS bucket
// histograms for both sorts, reserves per-(block,bucket) space with ONE
// global atomic, then scatters (keyLow, payload) entries.
__global__ __launch_bounds__(256) void binscat_kernel(const int* __restrict__ row,
                                                      const int* __restrict__ col,
                                                      int E, int NB,
                                                      int* __restrict__ ccur,
                                                      int2* __restrict__ b1,
                                                      int2* __restrict__ b2) {
    __shared__ int histC[NBMAX], histR[NBMAX];
    __shared__ int baseC[NBMAX], baseR[NBMAX];
    __shared__ int curC[NBMAX],  curR[NBMAX];
    int t  = threadIdx.x;
    int e0 = blockIdx.x * CE;
    int e1 = min(e0 + CE, E);

    for (int b = t; b < NB; b += 256) { histC[b] = 0; histR[b] = 0; }
    __syncthreads();
    for (int i = e0 + t; i < e1; i += 256) {
        atomicAdd(&histC[col[i] >> 7], 1);
        atomicAdd(&histR[row[i] >> 7], 1);
    }
    __syncthreads();
    for (int b = t; b < NB; b += 256) {
        int hc = histC[b];
        if (hc) baseC[b] = atomicAdd(&ccur[b], hc);
        int hr = histR[b];
        if (hr) baseR[b] = atomicAdd(&ccur[NB + b], hr);
        curC[b] = 0;
        curR[b] = 0;
    }
    __syncthreads();
    for (int i = e0 + t; i < e1; i += 256) {
        int c = col[i], r = row[i];
        int bc = c >> 7, br = r >> 7;
        int rc = atomicAdd(&curC[bc], 1);
        b1[baseC[bc] + rc] = make_int2(c & 127, r);     // (dstLow, src)
        int rr = atomicAdd(&curR[br], 1);
        b2[baseR[br] + rr] = make_int2(r & 127, i);     // (srcLow, eid)
    }
}

// Phase D: one workgroup per (sort, bucket). Init 128 LDS cursors from the
// fine offsets, place each bucket entry via LDS atomic, write final CSR
// entry into the bucket's exclusive output window (XCD-local lines).
__global__ __launch_bounds__(256) void place_kernel(const int2* __restrict__ b1,
                                                    const int2* __restrict__ b2,
                                                    const int* __restrict__ cbase,
                                                    const int* __restrict__ ccnt,
                                                    const int* __restrict__ offs,
                                                    const float* __restrict__ dinv,
                                                    int N, int NB, int E,
                                                    int2* __restrict__ ent,
                                                    int* __restrict__ eid) {
    __shared__ int cur[128];
    int bi  = blockIdx.x;
    int srt = bi / NB;
    int bk  = bi % NB;
    int t   = threadIdx.x;
    if (t < 128) {
        int node = bk * 128 + t;
        if (node < N) cur[t] = (srt == 0) ? offs[node] : offs[N + node] - E;
    }
    __syncthreads();
    int base = cbase[bi], count = ccnt[bi];
    if (srt == 0) {
        for (int j = t; j < count; j += 256) {
            int2 e  = b1[base + j];
            int node = bk * 128 + e.x;
            int pos  = atomicAdd(&cur[e.x], 1);
            ent[pos] = make_int2(e.y, __float_as_int(dinv[e.y] * dinv[node]));
        }
    } else {
        for (int j = t; j < count; j += 256) {
            int2 e  = b2[base + j];
            int pos = atomicAdd(&cur[e.x], 1);
            eid[pos] = e.y;
        }
    }
}

// agg[n] = sum of edge_attr rows over out-edges of n (row-CSR gather, no atomics)
__global__ __launch_bounds__(256) void aggr_kernel(const float* __restrict__ ea,
                                                   const int* __restrict__ offs,
                                                   const int* __restrict__ eid,
                                                   int N, int E,
                                                   float* __restrict__ agg) {
    int wid  = threadIdx.x >> 6;
    int lane = threadIdx.x & 63;
    int n = blockIdx.x * 4 + wid;
    if (n >= N) return;
    int f  = lane & 31;
    int hh = lane >> 5;
    int r0 = offs[N + n] - E;
    int r1 = offs[N + n + 1] - E;
    float s = 0.f;
    int e = r0 + hh;
    for (; e + 2 < r1; e += 4) {     // each half-wave: e, e+2 in flight
        float x0 = ea[(size_t)eid[e] * F_EDGE + f];
        float x1 = ea[(size_t)eid[e + 2] * F_EDGE + f];
        s += x0 + x1;
    }
    if (e < r1) s += ea[(size_t)eid[e] * F_EDGE + f];
    s += __shfl(s, lane ^ 32);
    if (hh == 0) agg[(size_t)n * F_EDGE + f] = s;
}

// ---------------------------------------------------------------------------
// GEMM: out[N,F] = concat(A[N,128], B[N,32]) @ W[160,F]
// ---------------------------------------------------------------------------
template <int F, int BN, int TX>
__global__ __launch_bounds__(256) void gemm_kernel(const float* __restrict__ A,
                                                   const float* __restrict__ B,
                                                   const float* __restrict__ W,
                                                   float* __restrict__ outp, int N) {
    constexpr int TY  = 256 / TX;
    constexpr int NPT = BN / TY;
    constexpr int KC  = 32;
    constexpr int IST = KC + 4;
    constexpr int WST = F + 4;
    __shared__ float in_lds[BN][IST];
    __shared__ float w_lds[KC][WST];

    int t  = threadIdx.x;
    int tx = t % TX;
    int ty = t / TX;
    int n0 = blockIdx.x * BN;
    int j0 = tx * 8;

    float acc[NPT][8];
#pragma unroll
    for (int i = 0; i < NPT; ++i)
#pragma unroll
        for (int f = 0; f < 8; ++f) acc[i][f] = 0.f;

    for (int c = 0; c < 5; ++c) {
        const float* src = (c < 4) ? (A + c * KC) : B;
        int stride = (c < 4) ? F_NODE : F_EDGE;
        for (int l = t; l < BN * 8; l += 256) {
            int rr = l >> 3;
            int cc = (l & 7) * 4;
            int n = n0 + rr;
            if (n >= N) n = N - 1;
            float4 v = *(const float4*)(src + (size_t)n * stride + cc);
            *(float4*)&in_lds[rr][cc] = v;
        }
        for (int l = t; l < KC * F / 4; l += 256) {
            int rr = l / (F / 4);
            int cc = (l % (F / 4)) * 4;
            float4 v = *(const float4*)(W + (size_t)(c * KC + rr) * F + cc);
            *(float4*)&w_lds[rr][cc] = v;
        }
        __syncthreads();

#pragma unroll
        for (int kk = 0; kk < KC; kk += 4) {
            float4 a4[NPT];
#pragma unroll
            for (int i = 0; i < NPT; ++i)
                a4[i] = *(const float4*)&in_lds[ty * NPT + i][kk];
#pragma unroll
            for (int p = 0; p < 4; ++p) {
                float4 wa = *(const float4*)&w_lds[kk + p][j0];
                float4 wb = *(const float4*)&w_lds[kk + p][j0 + 4];
#pragma unroll
                for (int i = 0; i < NPT; ++i) {
                    float a = (p == 0) ? a4[i].x : (p == 1) ? a4[i].y
                              : (p == 2) ? a4[i].z : a4[i].w;
                    acc[i][0] = fmaf(a, wa.x, acc[i][0]);
                    acc[i][1] = fmaf(a, wa.y, acc[i][1]);
                    acc[i][2] = fmaf(a, wa.z, acc[i][2]);
                    acc[i][3] = fmaf(a, wa.w, acc[i][3]);
                    acc[i][4] = fmaf(a, wb.x, acc[i][4]);
                    acc[i][5] = fmaf(a, wb.y, acc[i][5]);
                    acc[i][6] = fmaf(a, wb.z, acc[i][6]);
                    acc[i][7] = fmaf(a, wb.w, acc[i][7]);
                }
            }
        }
        __syncthreads();
    }

#pragma unroll
    for (int i = 0; i < NPT; ++i) {
        int n = n0 + ty * NPT + i;
        if (n < N) {
            *(float4*)(outp + (size_t)n * F + j0) =
                make_float4(acc[i][0], acc[i][1], acc[i][2], acc[i][3]);
            *(float4*)(outp + (size_t)n * F + j0 + 4) =
                make_float4(acc[i][4], acc[i][5], acc[i][6], acc[i][7]);
        }
    }
}

// ---------------------------------------------------------------------------
// Conv aggregation: out[n] = sum_{e: dst==n} norm_e * h[src_e] + dinv[n]^2*h[n] + b
// One wave per node; CSR gather, 4 gathers in flight (ILP unroll).
// ---------------------------------------------------------------------------
template <int F, bool RELU>
__global__ __launch_bounds__(256) void conv_kernel(const float* __restrict__ h,
                                                   const int* __restrict__ offs,
                                                   const int2* __restrict__ ent,
                                                   const float* __restrict__ dinv,
                                                   const float* __restrict__ bias,
                                                   float* __restrict__ outp, int N) {
    int wid  = threadIdx.x >> 6;
    int lane = threadIdx.x & 63;
    int n = blockIdx.x * 4 + wid;
    if (n >= N) return;
    float dn = dinv[n];
    float sw = dn * dn;
    int e0 = offs[n], e1 = offs[n + 1];

    if constexpr (F == 128) {
        float2 hv = *((const float2*)(h + (size_t)n * F) + lane);
        float a0 = sw * hv.x, a1 = sw * hv.y;
        int e = e0;
        for (; e + 4 <= e1; e += 4) {
            int2 p0 = ent[e], p1 = ent[e + 1], p2 = ent[e + 2], p3 = ent[e + 3];
            float2 v0 = *((const float2*)(h + (size_t)p0.x * F) + lane);
            float2 v1 = *((const float2*)(h + (size_t)p1.x * F) + lane);
            float2 v2 = *((const float2*)(h + (size_t)p2.x * F) + lane);
            float2 v3 = *((const float2*)(h + (size_t)p3.x * F) + lane);
            float w0 = __int_as_float(p0.y), w1 = __int_as_float(p1.y);
            float w2 = __int_as_float(p2.y), w3 = __int_as_float(p3.y);
            a0 = fmaf(w0, v0.x, a0); a1 = fmaf(w0, v0.y, a1);
            a0 = fmaf(w1, v1.x, a0); a1 = fmaf(w1, v1.y, a1);
            a0 = fmaf(w2, v2.x, a0); a1 = fmaf(w2, v2.y, a1);
            a0 = fmaf(w3, v3.x, a0); a1 = fmaf(w3, v3.y, a1);
        }
        for (; e < e1; ++e) {
            int2 pr = ent[e];
            float w = __int_as_float(pr.y);
            float2 v = *((const float2*)(h + (size_t)pr.x * F) + lane);
            a0 = fmaf(w, v.x, a0);
            a1 = fmaf(w, v.y, a1);
        }
        float2 bv = *((const float2*)bias + lane);
        a0 += bv.x;
        a1 += bv.y;
        if (RELU) { a0 = fmaxf(a0, 0.f); a1 = fmaxf(a1, 0.f); }
        *((float2*)(outp + (size_t)n * F) + lane) = make_float2(a0, a1);
    } else {
        float a0 = sw * h[(size_t)n * F + lane];
        int e = e0;
        for (; e + 4 <= e1; e += 4) {
            int2 p0 = ent[e], p1 = ent[e + 1], p2 = ent[e + 2], p3 = ent[e + 3];
            float v0 = h[(size_t)p0.x * F + lane];
            float v1 = h[(size_t)p1.x * F + lane];
            float v2 = h[(size_t)p2.x * F + lane];
            float v3 = h[(size_t)p3.x * F + lane];
            a0 = fmaf(__int_as_float(p0.y), v0, a0);
            a0 = fmaf(__int_as_float(p1.y), v1, a0);
            a0 = fmaf(__int_as_float(p2.y), v2, a0);
            a0 = fmaf(__int_as_float(p3.y), v3, a0);
        }
        for (; e < e1; ++e) {
            int2 pr = ent[e];
            a0 = fmaf(__int_as_float(pr.y), h[(size_t)pr.x * F + lane], a0);
        }
        a0 += bias[lane];
        if (RELU) a0 = fmaxf(a0, 0.f);
        outp[(size_t)n * F + lane] = a0;
    }
}

// ---------------------------------------------------------------------------
extern "C" void kernel_launch(void* const* d_in, const int* in_sizes, int n_in,
                              void* d_out, int out_size, void* d_ws, size_t ws_size,
                              hipStream_t stream) {
    const float* x  = (const float*)d_in[0];
    const void*  ei = d_in[1];
    const float* ea = (const float*)d_in[2];
    const float* w1 = (const float*)d_in[3];
    const float* b1 = (const float*)d_in[4];
    const float* w2 = (const float*)d_in[5];
    const float* b2 = (const float*)d_in[6];
    float* out = (float*)d_out;

    int N = in_sizes[0] / F_NODE;
    int E = in_sizes[1] / 2;
    int NB = (N + 127) >> 7;              // coarse buckets (782 for N=100K)

    char* ws = (char*)d_ws;
    size_t off = 0;
    auto alloc = [&](size_t bytes) -> void* {
        void* p = ws + off;
        off = (off + bytes + 255) & ~(size_t)255;
        return p;
    };

    int*   flag  = (int*)alloc(256);
    int*   row   = (int*)alloc((size_t)E * 4);
    int*   col   = (int*)alloc((size_t)E * 4);
    int*   cnt   = (int*)alloc((size_t)2 * N * 4);
    int*   offs  = (int*)alloc((size_t)(2 * N + 1) * 4);
    float* dinv  = (float*)alloc((size_t)N * 4);
    int*   bsum  = (int*)alloc(4096);
    int*   ccnt  = (int*)alloc((size_t)2 * NBMAX * 4);
    int*   cbase = (int*)alloc((size_t)2 * NBMAX * 4);
    int*   ccur  = (int*)alloc((size_t)2 * NBMAX * 4);
    int2*  ent   = (int2*)alloc((size_t)E * 8);
    int*   eid   = (int*)alloc((size_t)E * 4);
    float* agg   = (float*)alloc((size_t)N * F_EDGE * 4);
    float* h1    = (float*)alloc((size_t)N * HID * 4);
    float* hr    = (float*)alloc((size_t)N * HID * 4);
    float* h2    = (float*)alloc((size_t)N * OUTF * 4);

    // Bucket staging arrays alias h1 (dead until gemm1, which runs after place).
    int2* bkt1 = (int2*)h1;                       // E * 8 bytes
    int2* bkt2 = (int2*)(h1 + (size_t)2 * E);     // E * 8 bytes (h1 is 51.2MB >= 25.6MB)

    int gE = (E + 255) / 256;
    int M  = 2 * N;
    int gM = (M + 255) / 256;
    int nb = (M + 1023) / 1024;

    detect_kernel<<<1, 64, 0, stream>>>(ei, N, flag);
    decode_kernel<<<gE, 256, 0, stream>>>(ei, E, N, flag, row, col);
    zero_kernel<<<gM, 256, 0, stream>>>(cnt, M);
    hist_kernel<<<gE, 256, 0, stream>>>(row, col, E, N, cnt);
    scan1_kernel<<<nb, 1024, 0, stream>>>(cnt, M, offs, bsum);
    scan2_kernel<<<1, 1024, 0, stream>>>(bsum, nb);
    scan3_kernel<<<gM, 256, 0, stream>>>(offs, M, bsum);
    dinv_kernel<<<(N + 255) / 256, 256, 0, stream>>>(cnt, N, dinv);
    coarse_cnt_kernel<<<2 * NB, 128, 0, stream>>>(cnt, N, NB, ccnt);
    coarse_scan_kernel<<<1, 1024, 0, stream>>>(ccnt, NB, cbase, ccur);
    binscat_kernel<<<(E + CE - 1) / CE, 256, 0, stream>>>(row, col, E, NB, ccur, bkt1, bkt2);
    place_kernel<<<2 * NB, 256, 0, stream>>>(bkt1, bkt2, cbase, ccnt, offs, dinv,
                                             N, NB, E, ent, eid);
    aggr_kernel<<<(N + 3) / 4, 256, 0, stream>>>(ea, offs, eid, N, E, agg);

    gemm_kernel<HID, 64, 16><<<(N + 63) / 64, 256, 0, stream>>>(x, agg, w1, h1, N);
    conv_kernel<HID, true><<<(N + 3) / 4, 256, 0, stream>>>(h1, offs, ent, dinv, b1, hr, N);
    gemm_kernel<OUTF, 128, 8><<<(N + 127) / 128, 256, 0, stream>>>(hr, agg, w2, h2, N);
    conv_kernel<OUTF, false><<<(N + 3) / 4, 256, 0, stream>>>(h2, offs, ent, dinv, b2, out, N);
}

// Round 7
// 791.527 us; speedup vs baseline: 1.2797x; 1.1510x over previous
//
#include <hip/hip_runtime.h>
#include <stdint.h>

#define F_NODE 128
#define F_EDGE 32
#define HID    128
#define OUTF   64

#define NBMAX  1024     // max coarse buckets (supports N <= 131072)
#define CE     16384    // edges per chunk for decode/binscat blocks

// ---------------------------------------------------------------------------
// Preprocessing
// ---------------------------------------------------------------------------

// Detect whether edge_index is int64 (reference dtype) or int32.
__global__ void detect_kernel(const void* ei, int N, int* flag) {
    const long long* p64 = (const long long*)ei;
    int t = threadIdx.x;
    long long v = p64[t];
    int ok = (v >= 0 && v < (long long)N) ? 1 : 0;
    unsigned long long m = __ballot(ok);
    if (t == 0) *flag = (__popcll(m) >= 32) ? 1 : 0;
}

__global__ void zero_kernel(int* p, int n) {
    int i = blockIdx.x * blockDim.x + threadIdx.x;
    if (i < n) p[i] = 0;
}

// Decode edge_index to row/col AND build the coarse bucket histogram
// (LDS-first; ~153K global atomics total on a 6.3KB array — L2-resident).
__global__ __launch_bounds__(256) void decode_hist_kernel(const void* ei, int E, int N,
                                                          int NB, const int* flag,
                                                          int* __restrict__ row,
                                                          int* __restrict__ col,
                                                          int* __restrict__ ccnt) {
    __shared__ int hC[NBMAX], hR[NBMAX];
    int t = threadIdx.x;
    for (int b = t; b < NB; b += 256) { hC[b] = 0; hR[b] = 0; }
    __syncthreads();
    int e0 = blockIdx.x * CE;
    int e1 = min(e0 + CE, E);
    bool wide = (*flag != 0);
    for (int i = e0 + t; i < e1; i += 256) {
        int r, c;
        if (wide) {
            const long long* p = (const long long*)ei;
            r = (int)p[i];
            c = (int)p[E + i];
        } else {
            const int* p = (const int*)ei;
            r = p[i];
            c = p[E + i];
        }
        r = min(max(r, 0), N - 1);
        c = min(max(c, 0), N - 1);
        row[i] = r;
        col[i] = c;
        atomicAdd(&hC[c >> 7], 1);
        atomicAdd(&hR[r >> 7], 1);
    }
    __syncthreads();
    for (int b = t; b < NB; b += 256) {
        if (hC[b]) atomicAdd(&ccnt[b], hC[b]);
        if (hR[b]) atomicAdd(&ccnt[NB + b], hR[b]);
    }
}

// Exclusive scan of each NB-segment of ccnt -> cbase (and cursor copy ccur)
__global__ void coarse_scan_kernel(const int* __restrict__ ccnt, int NB,
                                   int* __restrict__ cbase, int* __restrict__ ccur) {
    __shared__ int s[1024];
    int t = threadIdx.x;
    for (int seg = 0; seg < 2; ++seg) {
        int v = (t < NB) ? ccnt[seg * NB + t] : 0;
        s[t] = v;
        __syncthreads();
        for (int d = 1; d < 1024; d <<= 1) {
            int x = (t >= d) ? s[t - d] : 0;
            __syncthreads();
            s[t] += x;
            __syncthreads();
        }
        if (t < NB) {
            int ex = s[t] - v;
            cbase[seg * NB + t] = ex;
            ccur[seg * NB + t]  = ex;
        }
        __syncthreads();
    }
}

// Binned scatter: each block takes CE edges, builds LDS bucket histograms for
// both sorts, reserves per-(block,bucket) space with ONE global atomic, then
// scatters (keyLow, payload) entries into bucket regions.
__global__ __launch_bounds__(256) void binscat_kernel(const int* __restrict__ row,
                                                      const int* __restrict__ col,
                                                      int E, int NB,
                                                      int* __restrict__ ccur,
                                                      int2* __restrict__ b1,
                                                      int2* __restrict__ b2) {
    __shared__ int histC[NBMAX], histR[NBMAX];
    __shared__ int baseC[NBMAX], baseR[NBMAX];
    __shared__ int curC[NBMAX],  curR[NBMAX];
    int t  = threadIdx.x;
    int e0 = blockIdx.x * CE;
    int e1 = min(e0 + CE, E);

    for (int b = t; b < NB; b += 256) { histC[b] = 0; histR[b] = 0; }
    __syncthreads();
    for (int i = e0 + t; i < e1; i += 256) {
        atomicAdd(&histC[col[i] >> 7], 1);
        atomicAdd(&histR[row[i] >> 7], 1);
    }
    __syncthreads();
    for (int b = t; b < NB; b += 256) {
        int hc = histC[b];
        if (hc) baseC[b] = atomicAdd(&ccur[b], hc);
        int hr = histR[b];
        if (hr) baseR[b] = atomicAdd(&ccur[NB + b], hr);
        curC[b] = 0;
        curR[b] = 0;
    }
    __syncthreads();
    for (int i = e0 + t; i < e1; i += 256) {
        int c = col[i], r = row[i];
        int bc = c >> 7, br = r >> 7;
        int rc = atomicAdd(&curC[bc], 1);
        b1[baseC[bc] + rc] = make_int2(c & 127, r);     // (dstLow, src)
        int rr = atomicAdd(&curR[br], 1);
        b2[baseR[br] + rr] = make_int2(r & 127, i);     // (srcLow, eid)
    }
}

// Fused per-bucket build: LDS fine histogram -> LDS scan -> write CSR offsets
// (+dinv for the dst sort) -> scatter entries into the bucket's exclusive
// output window. No global scan, no global atomics.
__global__ __launch_bounds__(256) void build_kernel(const int2* __restrict__ b1,
                                                    const int2* __restrict__ b2,
                                                    const int* __restrict__ cbase,
                                                    const int* __restrict__ ccnt,
                                                    int NB, int N, int E,
                                                    int* __restrict__ doff,
                                                    int* __restrict__ roff,
                                                    float* __restrict__ dinv,
                                                    int* __restrict__ ents,
                                                    int* __restrict__ eid) {
    __shared__ int h[128];
    __shared__ int sc[128];
    __shared__ int cur[128];
    int bi  = blockIdx.x;
    int srt = bi / NB;
    int bk  = bi % NB;
    int t   = threadIdx.x;
    const int2* src = (srt == 0) ? b1 : b2;
    int base  = cbase[bi];
    int count = ccnt[bi];

    if (t < 128) h[t] = 0;
    __syncthreads();
    for (int j = t; j < count; j += 256) atomicAdd(&h[src[base + j].x], 1);
    __syncthreads();
    if (t < 128) sc[t] = h[t];
    __syncthreads();
    for (int d = 1; d < 128; d <<= 1) {
        int x = (t < 128 && t >= d) ? sc[t - d] : 0;
        __syncthreads();
        if (t < 128) sc[t] += x;
        __syncthreads();
    }
    if (t < 128) {
        int node = bk * 128 + t;
        if (node < N) {
            int o = base + sc[t] - h[t];     // exclusive within bucket
            cur[t] = o;
            if (srt == 0) {
                doff[node] = o;
                dinv[node] = rsqrtf((float)(h[t] + 1));   // in-degree + self loop
            } else {
                roff[node] = o;
            }
        }
    }
    if (t == 0 && bk == 0) {
        if (srt == 0) doff[N] = E; else roff[N] = E;
    }
    __syncthreads();
    if (srt == 0) {
        for (int j = t; j < count; j += 256) {
            int2 e = src[base + j];
            int pos = atomicAdd(&cur[e.x], 1);
            ents[pos] = e.y;
        }
    } else {
        for (int j = t; j < count; j += 256) {
            int2 e = src[base + j];
            int pos = atomicAdd(&cur[e.x], 1);
            eid[pos] = e.y;
        }
    }
}

// agg[n] = sum of edge_attr rows over out-edges of n (row-CSR gather)
__global__ __launch_bounds__(256) void aggr_kernel(const float* __restrict__ ea,
                                                   const int* __restrict__ roff,
                                                   const int* __restrict__ eid,
                                                   int N,
                                                   float* __restrict__ agg) {
    int wid  = threadIdx.x >> 6;
    int lane = threadIdx.x & 63;
    int n = blockIdx.x * 4 + wid;
    if (n >= N) return;
    int f  = lane & 31;
    int hh = lane >> 5;
    int r0 = roff[n];
    int r1 = roff[n + 1];
    float s = 0.f;
    int e = r0 + hh;
    for (; e + 2 < r1; e += 4) {     // each half-wave: e, e+2 in flight
        float x0 = ea[(size_t)eid[e] * F_EDGE + f];
        float x1 = ea[(size_t)eid[e + 2] * F_EDGE + f];
        s += x0 + x1;
    }
    if (e < r1) s += ea[(size_t)eid[e] * F_EDGE + f];
    s += __shfl(s, lane ^ 32);
    if (hh == 0) agg[(size_t)n * F_EDGE + f] = s;
}

// ---------------------------------------------------------------------------
// GEMM: out[N,F] = concat(A[N,128], B[N,32]) @ W[160,F]
// ---------------------------------------------------------------------------
template <int F, int BN, int TX>
__global__ __launch_bounds__(256) void gemm_kernel(const float* __restrict__ A,
                                                   const float* __restrict__ B,
                                                   const float* __restrict__ W,
                                                   float* __restrict__ outp, int N) {
    constexpr int TY  = 256 / TX;
    constexpr int NPT = BN / TY;
    constexpr int KC  = 32;
    constexpr int IST = KC + 4;
    constexpr int WST = F + 4;
    __shared__ float in_lds[BN][IST];
    __shared__ float w_lds[KC][WST];

    int t  = threadIdx.x;
    int tx = t % TX;
    int ty = t / TX;
    int n0 = blockIdx.x * BN;
    int j0 = tx * 8;

    float acc[NPT][8];
#pragma unroll
    for (int i = 0; i < NPT; ++i)
#pragma unroll
        for (int f = 0; f < 8; ++f) acc[i][f] = 0.f;

    for (int c = 0; c < 5; ++c) {
        const float* src = (c < 4) ? (A + c * KC) : B;
        int stride = (c < 4) ? F_NODE : F_EDGE;
        for (int l = t; l < BN * 8; l += 256) {
            int rr = l >> 3;
            int cc = (l & 7) * 4;
            int n = n0 + rr;
            if (n >= N) n = N - 1;
            float4 v = *(const float4*)(src + (size_t)n * stride + cc);
            *(float4*)&in_lds[rr][cc] = v;
        }
        for (int l = t; l < KC * F / 4; l += 256) {
            int rr = l / (F / 4);
            int cc = (l % (F / 4)) * 4;
            float4 v = *(const float4*)(W + (size_t)(c * KC + rr) * F + cc);
            *(float4*)&w_lds[rr][cc] = v;
        }
        __syncthreads();

#pragma unroll
        for (int kk = 0; kk < KC; kk += 4) {
            float4 a4[NPT];
#pragma unroll
            for (int i = 0; i < NPT; ++i)
                a4[i] = *(const float4*)&in_lds[ty * NPT + i][kk];
#pragma unroll
            for (int p = 0; p < 4; ++p) {
                float4 wa = *(const float4*)&w_lds[kk + p][j0];
                float4 wb = *(const float4*)&w_lds[kk + p][j0 + 4];
#pragma unroll
                for (int i = 0; i < NPT; ++i) {
                    float a = (p == 0) ? a4[i].x : (p == 1) ? a4[i].y
                              : (p == 2) ? a4[i].z : a4[i].w;
                    acc[i][0] = fmaf(a, wa.x, acc[i][0]);
                    acc[i][1] = fmaf(a, wa.y, acc[i][1]);
                    acc[i][2] = fmaf(a, wa.z, acc[i][2]);
                    acc[i][3] = fmaf(a, wa.w, acc[i][3]);
                    acc[i][4] = fmaf(a, wb.x, acc[i][4]);
                    acc[i][5] = fmaf(a, wb.y, acc[i][5]);
                    acc[i][6] = fmaf(a, wb.z, acc[i][6]);
                    acc[i][7] = fmaf(a, wb.w, acc[i][7]);
                }
            }
        }
        __syncthreads();
    }

#pragma unroll
    for (int i = 0; i < NPT; ++i) {
        int n = n0 + ty * NPT + i;
        if (n < N) {
            *(float4*)(outp + (size_t)n * F + j0) =
                make_float4(acc[i][0], acc[i][1], acc[i][2], acc[i][3]);
            *(float4*)(outp + (size_t)n * F + j0 + 4) =
                make_float4(acc[i][4], acc[i][5], acc[i][6], acc[i][7]);
        }
    }
}

// ---------------------------------------------------------------------------
// Conv aggregation: out[n] = sum_{e: dst==n} dinv[src]*dinv[n]*h[src] +
//                   dinv[n]^2*h[n] + bias.  Norm computed on the fly.
// One wave per node; CSR gather, 8 gathers in flight.
// ---------------------------------------------------------------------------
template <int F, bool RELU>
__global__ __launch_bounds__(256) void conv_kernel(const float* __restrict__ h,
                                                   const int* __restrict__ doff,
                                                   const int* __restrict__ ents,
                                                   const float* __restrict__ dinv,
                                                   const float* __restrict__ bias,
                                                   float* __restrict__ outp, int N) {
    int wid  = threadIdx.x >> 6;
    int lane = threadIdx.x & 63;
    int n = blockIdx.x * 4 + wid;
    if (n >= N) return;
    float dn = dinv[n];
    float sw = dn * dn;
    int e0 = doff[n], e1 = doff[n + 1];

    if constexpr (F == 128) {
        float2 hv = *((const float2*)(h + (size_t)n * F) + lane);
        float a0 = sw * hv.x, a1 = sw * hv.y;
        int e = e0;
        for (; e + 8 <= e1; e += 8) {
            int s0 = ents[e],     s1 = ents[e + 1], s2 = ents[e + 2], s3 = ents[e + 3];
            int s4 = ents[e + 4], s5 = ents[e + 5], s6 = ents[e + 6], s7 = ents[e + 7];
            float2 v0 = *((const float2*)(h + (size_t)s0 * F) + lane);
            float2 v1 = *((const float2*)(h + (size_t)s1 * F) + lane);
            float2 v2 = *((const float2*)(h + (size_t)s2 * F) + lane);
            float2 v3 = *((const float2*)(h + (size_t)s3 * F) + lane);
            float2 v4 = *((const float2*)(h + (size_t)s4 * F) + lane);
            float2 v5 = *((const float2*)(h + (size_t)s5 * F) + lane);
            float2 v6 = *((const float2*)(h + (size_t)s6 * F) + lane);
            float2 v7 = *((const float2*)(h + (size_t)s7 * F) + lane);
            float w0 = dinv[s0] * dn, w1 = dinv[s1] * dn;
            float w2 = dinv[s2] * dn, w3 = dinv[s3] * dn;
            float w4 = dinv[s4] * dn, w5 = dinv[s5] * dn;
            float w6 = dinv[s6] * dn, w7 = dinv[s7] * dn;
            a0 = fmaf(w0, v0.x, a0); a1 = fmaf(w0, v0.y, a1);
            a0 = fmaf(w1, v1.x, a0); a1 = fmaf(w1, v1.y, a1);
            a0 = fmaf(w2, v2.x, a0); a1 = fmaf(w2, v2.y, a1);
            a0 = fmaf(w3, v3.x, a0); a1 = fmaf(w3, v3.y, a1);
            a0 = fmaf(w4, v4.x, a0); a1 = fmaf(w4, v4.y, a1);
            a0 = fmaf(w5, v5.x, a0); a1 = fmaf(w5, v5.y, a1);
            a0 = fmaf(w6, v6.x, a0); a1 = fmaf(w6, v6.y, a1);
            a0 = fmaf(w7, v7.x, a0); a1 = fmaf(w7, v7.y, a1);
        }
        for (; e + 4 <= e1; e += 4) {
            int s0 = ents[e], s1 = ents[e + 1], s2 = ents[e + 2], s3 = ents[e + 3];
            float2 v0 = *((const float2*)(h + (size_t)s0 * F) + lane);
            float2 v1 = *((const float2*)(h + (size_t)s1 * F) + lane);
            float2 v2 = *((const float2*)(h + (size_t)s2 * F) + lane);
            float2 v3 = *((const float2*)(h + (size_t)s3 * F) + lane);
            float w0 = dinv[s0] * dn, w1 = dinv[s1] * dn;
            float w2 = dinv[s2] * dn, w3 = dinv[s3] * dn;
            a0 = fmaf(w0, v0.x, a0); a1 = fmaf(w0, v0.y, a1);
            a0 = fmaf(w1, v1.x, a0); a1 = fmaf(w1, v1.y, a1);
            a0 = fmaf(w2, v2.x, a0); a1 = fmaf(w2, v2.y, a1);
            a0 = fmaf(w3, v3.x, a0); a1 = fmaf(w3, v3.y, a1);
        }
        for (; e < e1; ++e) {
            int s = ents[e];
            float w = dinv[s] * dn;
            float2 v = *((const float2*)(h + (size_t)s * F) + lane);
            a0 = fmaf(w, v.x, a0);
            a1 = fmaf(w, v.y, a1);
        }
        float2 bv = *((const float2*)bias + lane);
        a0 += bv.x;
        a1 += bv.y;
        if (RELU) { a0 = fmaxf(a0, 0.f); a1 = fmaxf(a1, 0.f); }
        *((float2*)(outp + (size_t)n * F) + lane) = make_float2(a0, a1);
    } else {
        float a0 = sw * h[(size_t)n * F + lane];
        int e = e0;
        for (; e + 8 <= e1; e += 8) {
            int s0 = ents[e],     s1 = ents[e + 1], s2 = ents[e + 2], s3 = ents[e + 3];
            int s4 = ents[e + 4], s5 = ents[e + 5], s6 = ents[e + 6], s7 = ents[e + 7];
            float v0 = h[(size_t)s0 * F + lane];
            float v1 = h[(size_t)s1 * F + lane];
            float v2 = h[(size_t)s2 * F + lane];
            float v3 = h[(size_t)s3 * F + lane];
            float v4 = h[(size_t)s4 * F + lane];
            float v5 = h[(size_t)s5 * F + lane];
            float v6 = h[(size_t)s6 * F + lane];
            float v7 = h[(size_t)s7 * F + lane];
            a0 = fmaf(dinv[s0] * dn, v0, a0);
            a0 = fmaf(dinv[s1] * dn, v1, a0);
            a0 = fmaf(dinv[s2] * dn, v2, a0);
            a0 = fmaf(dinv[s3] * dn, v3, a0);
            a0 = fmaf(dinv[s4] * dn, v4, a0);
            a0 = fmaf(dinv[s5] * dn, v5, a0);
            a0 = fmaf(dinv[s6] * dn, v6, a0);
            a0 = fmaf(dinv[s7] * dn, v7, a0);
        }
        for (; e + 4 <= e1; e += 4) {
            int s0 = ents[e], s1 = ents[e + 1], s2 = ents[e + 2], s3 = ents[e + 3];
            float v0 = h[(size_t)s0 * F + lane];
            float v1 = h[(size_t)s1 * F + lane];
            float v2 = h[(size_t)s2 * F + lane];
            float v3 = h[(size_t)s3 * F + lane];
            a0 = fmaf(dinv[s0] * dn, v0, a0);
            a0 = fmaf(dinv[s1] * dn, v1, a0);
            a0 = fmaf(dinv[s2] * dn, v2, a0);
            a0 = fmaf(dinv[s3] * dn, v3, a0);
        }
        for (; e < e1; ++e) {
            int s = ents[e];
            a0 = fmaf(dinv[s] * dn, h[(size_t)s * F + lane], a0);
        }
        a0 += bias[lane];
        if (RELU) a0 = fmaxf(a0, 0.f);
        outp[(size_t)n * F + lane] = a0;
    }
}

// ---------------------------------------------------------------------------
extern "C" void kernel_launch(void* const* d_in, const int* in_sizes, int n_in,
                              void* d_out, int out_size, void* d_ws, size_t ws_size,
                              hipStream_t stream) {
    const float* x  = (const float*)d_in[0];
    const void*  ei = d_in[1];
    const float* ea = (const float*)d_in[2];
    const float* w1 = (const float*)d_in[3];
    const float* b1 = (const float*)d_in[4];
    const float* w2 = (const float*)d_in[5];
    const float* b2 = (const float*)d_in[6];
    float* out = (float*)d_out;

    int N = in_sizes[0] / F_NODE;
    int E = in_sizes[1] / 2;
    int NB = (N + 127) >> 7;              // coarse buckets (782 for N=100K)

    char* ws = (char*)d_ws;
    size_t off = 0;
    auto alloc = [&](size_t bytes) -> void* {
        void* p = ws + off;
        off = (off + bytes + 255) & ~(size_t)255;
        return p;
    };

    int*   flag  = (int*)alloc(256);
    int*   row   = (int*)alloc((size_t)E * 4);
    int*   col   = (int*)alloc((size_t)E * 4);
    int*   ccnt  = (int*)alloc((size_t)2 * NBMAX * 4);
    int*   cbase = (int*)alloc((size_t)2 * NBMAX * 4);
    int*   ccur  = (int*)alloc((size_t)2 * NBMAX * 4);
    int*   doff  = (int*)alloc((size_t)(N + 1) * 4);
    int*   roff  = (int*)alloc((size_t)(N + 1) * 4);
    float* dinv  = (float*)alloc((size_t)N * 4);
    int*   ents  = (int*)alloc((size_t)E * 4);
    int*   eid   = (int*)alloc((size_t)E * 4);
    float* agg   = (float*)alloc((size_t)N * F_EDGE * 4);
    float* h1    = (float*)alloc((size_t)N * HID * 4);
    float* hr    = (float*)alloc((size_t)N * HID * 4);
    float* h2    = (float*)alloc((size_t)N * OUTF * 4);

    // Bucket staging arrays alias h1 (dead until gemm1, which runs after build).
    int2* bkt1 = (int2*)h1;                       // E * 8 bytes
    int2* bkt2 = (int2*)(h1 + (size_t)2 * E);     // E * 8 bytes (h1 = 51.2MB >= 25.6MB)

    int nChunk = (E + CE - 1) / CE;

    detect_kernel<<<1, 64, 0, stream>>>(ei, N, flag);
    zero_kernel<<<(2 * NB + 255) / 256, 256, 0, stream>>>(ccnt, 2 * NB);
    decode_hist_kernel<<<nChunk, 256, 0, stream>>>(ei, E, N, NB, flag, row, col, ccnt);
    coarse_scan_kernel<<<1, 1024, 0, stream>>>(ccnt, NB, cbase, ccur);
    binscat_kernel<<<nChunk, 256, 0, stream>>>(row, col, E, NB, ccur, bkt1, bkt2);
    build_kernel<<<2 * NB, 256, 0, stream>>>(bkt1, bkt2, cbase, ccnt, NB, N, E,
                                             doff, roff, dinv, ents, eid);
    aggr_kernel<<<(N + 3) / 4, 256, 0, stream>>>(ea, roff, eid, N, agg);

    gemm_kernel<HID, 64, 16><<<(N + 63) / 64, 256, 0, stream>>>(x, agg, w1, h1, N);
    conv_kernel<HID, true><<<(N + 3) / 4, 256, 0, stream>>>(h1, doff, ents, dinv, b1, hr, N);
    gemm_kernel<OUTF, 128, 8><<<(N + 127) / 128, 256, 0, stream>>>(hr, agg, w2, h2, N);
    conv_kernel<OUTF, false><<<(N + 3) / 4, 256, 0, stream>>>(h2, doff, ents, dinv, b2, out, N);
}